// Round 2
// baseline (2662.515 us; speedup 1.0000x reference)
//
#include <hip/hip_runtime.h>
#include <hip/hip_bf16.h>

// GCSA: x(8,192,128,128) fp32 -> qkv 1x1 conv -> dw3x3 dil2 -> channel attn -> proj
// All external tensors fp32. Intermediate qkv_pre stored bf16 (2% tolerance).

#define DIM 192
#define NH 8
#define CH 24            // DIM/NH
#define IH 128
#define IW 128
#define NPIX (IH*IW)     // 16384
#define BATCH 8
#define QKVC (3*DIM)     // 576

typedef __hip_bfloat16 bf16;

__device__ __forceinline__ float b2f(bf16 v){ return __bfloat162float(v); }

// ---------------------------------------------------------------------------
// K1: qkv_pre[b][o][p] = sum_c Wqkv[o][c] * x[b][c][p]   (1x1 conv GEMM)
// grid (ptile=64, ochunk=12, b=8), block 256. Each thread: 1 pixel, 48 out-ch.
// ---------------------------------------------------------------------------
__global__ __launch_bounds__(256) void k1_qkv(const float* __restrict__ x,
        const float* __restrict__ wqkv, bf16* __restrict__ qkv_pre){
    __shared__ float Wl[48][DIM];          // 36 KB
    const int tid = threadIdx.x;
    const int pt = blockIdx.x, oc = blockIdx.y, b = blockIdx.z;
    const int obase = oc*48;
    for(int i = tid; i < 48*DIM; i += 256){
        int o = i / DIM, c = i % DIM;
        Wl[o][c] = wqkv[(obase+o)*DIM + c];
    }
    __syncthreads();
    const int p = pt*256 + tid;
    const float* xp = x + (size_t)b*DIM*NPIX + p;
    float acc[48];
    #pragma unroll
    for(int o=0;o<48;o++) acc[o]=0.f;
    #pragma unroll 2
    for(int c=0;c<DIM;c++){
        float xv = xp[(size_t)c*NPIX];
        #pragma unroll
        for(int o=0;o<48;o++) acc[o] += Wl[o][c]*xv;   // Wl broadcast, conflict-free
    }
    bf16* op = qkv_pre + ((size_t)b*QKVC + obase)*NPIX + p;
    #pragma unroll
    for(int o=0;o<48;o++) op[(size_t)o*NPIX] = __float2bfloat16(acc[o]);
}

// ---------------------------------------------------------------------------
// K2: per (b,h): Gram G[c][d] = sum_p q[c][p]*k[d][p] and row sum-squares.
// q,k = depthwise-conv(qkv_pre) computed on the fly. Atomic accumulation.
// grid (pchunk=64, h=8, b=8), block 256 (1 pixel/thread).
// ---------------------------------------------------------------------------
__global__ __launch_bounds__(256) void k2_gram(const bf16* __restrict__ qkv_pre,
        const float* __restrict__ wdw, float* __restrict__ G,
        float* __restrict__ sqq, float* __restrict__ sqk){
    __shared__ float ql[CH][257];   // +1 pad: column reads hit distinct banks
    __shared__ float kl[CH][257];
    const int tid = threadIdx.x;
    const int pc = blockIdx.x, h = blockIdx.y, b = blockIdx.z;
    const int p = pc*256 + tid;
    const int py = p >> 7, px = p & 127;
    for(int c=0;c<CH;c++){
        const int qch = h*CH + c;
        const int kch = DIM + qch;
        const bf16* qbase = qkv_pre + ((size_t)b*QKVC + qch)*NPIX;
        const bf16* kbase = qkv_pre + ((size_t)b*QKVC + kch)*NPIX;
        const float* wq = wdw + qch*9;
        const float* wk = wdw + kch*9;
        float qa=0.f, ka=0.f;
        #pragma unroll
        for(int ky=0;ky<3;ky++){
            int yy = py + 2*ky - 2;
            bool yok = (yy>=0)&&(yy<IH);
            #pragma unroll
            for(int kx=0;kx<3;kx++){
                int xx = px + 2*kx - 2;
                if(yok && xx>=0 && xx<IW){
                    int idx = yy*IW + xx;
                    qa += wq[ky*3+kx] * b2f(qbase[idx]);
                    ka += wk[ky*3+kx] * b2f(kbase[idx]);
                }
            }
        }
        ql[c][tid] = qa;
        kl[c][tid] = ka;
    }
    __syncthreads();
    float* Gp = G + ((size_t)(b*NH + h))*CH*CH;
    for(int pi = tid; pi < CH*CH; pi += 256){
        int c = pi / CH, d = pi % CH;
        float s = 0.f;
        for(int pp=0; pp<256; pp++) s += ql[c][pp]*kl[d][pp];
        atomicAdd(&Gp[pi], s);
    }
    if(tid < CH){
        float s=0.f;
        for(int pp=0;pp<256;pp++){ float v = ql[tid][pp]; s += v*v; }
        atomicAdd(&sqq[(b*NH+h)*CH + tid], s);
    } else if(tid < 2*CH){
        int c = tid - CH;
        float s=0.f;
        for(int pp=0;pp<256;pp++){ float v = kl[c][pp]; s += v*v; }
        atomicAdd(&sqk[(b*NH+h)*CH + c], s);
    }
}

// ---------------------------------------------------------------------------
// K3: logits = G/(||q_c||*||k_d||)*T[h]; softmax over d; fold with Wproj:
//     M[b][o][h*24+d] = sum_c Wproj[o][h*24+c] * attn[h][c][d]
// grid 8 (batch), block 256. Tiny.
// ---------------------------------------------------------------------------
__global__ __launch_bounds__(256) void k3_attn(const float* __restrict__ G,
        const float* __restrict__ sqq, const float* __restrict__ sqk,
        const float* __restrict__ temp, const float* __restrict__ wproj,
        float* __restrict__ M){
    __shared__ float attn[NH][CH][CH];   // 18.4 KB
    __shared__ float nq[DIM], nk[DIM];
    const int b = blockIdx.x, tid = threadIdx.x;
    if(tid < DIM){
        nq[tid] = fmaxf(sqrtf(sqq[b*DIM + tid]), 1e-12f);
        nk[tid] = fmaxf(sqrtf(sqk[b*DIM + tid]), 1e-12f);
    }
    __syncthreads();
    if(tid < DIM){
        int h = tid / CH, c = tid % CH;
        float t = temp[h];
        const float* g = G + ((size_t)(b*NH+h))*CH*CH + c*CH;
        float row[CH];
        float mx = -1e30f;
        #pragma unroll
        for(int d=0; d<CH; d++){
            float v = g[d] / (nq[h*CH+c]*nk[h*CH+d]) * t;
            row[d]=v; mx = fmaxf(mx,v);
        }
        float sum=0.f;
        #pragma unroll
        for(int d=0;d<CH;d++){ row[d]=expf(row[d]-mx); sum+=row[d]; }
        float inv = 1.f/sum;
        #pragma unroll
        for(int d=0;d<CH;d++) attn[h][c][d] = row[d]*inv;
    }
    __syncthreads();
    float* Mb = M + (size_t)b*DIM*DIM;
    for(int i = tid; i < DIM*DIM; i += 256){
        int o = i / DIM, hd = i % DIM;
        int h = hd / CH, d = hd % CH;
        float s = 0.f;
        #pragma unroll
        for(int c=0;c<CH;c++)
            s += wproj[o*DIM + h*CH + c] * attn[h][c][d];
        Mb[i] = s;
    }
}

// ---------------------------------------------------------------------------
// K5: out[b][o][p] = sum_hd M[b][o][hd] * v_post[b][hd][p]
// v_post = depthwise-conv(qkv_pre[ch 384..575]) computed on the fly into LDS.
// grid (ptile=256 of 64px, b=8), block 256 = 4 waves; wave g covers o-range
// g*48..g*48+47 for all 64 pixels of the tile.
// ---------------------------------------------------------------------------
__global__ __launch_bounds__(256) void k5_out(const bf16* __restrict__ qkv_pre,
        const float* __restrict__ wdw, const float* __restrict__ M,
        float* __restrict__ out){
    __shared__ float vl[DIM][64];   // 48 KB
    __shared__ float Ml[DIM][32];   // 24 KB
    const int tid = threadIdx.x;
    const int px_l = tid & 63, g = tid >> 6;
    const int pt = blockIdx.x, b = blockIdx.y;
    const int p = pt*64 + px_l;
    const int py = p >> 7, px = p & 127;
    // phase 1: each thread computes v_post for 48 channels at its pixel
    for(int j=0;j<48;j++){
        int hd = g*48 + j;
        int vch = 2*DIM + hd;
        const bf16* vbase = qkv_pre + ((size_t)b*QKVC + vch)*NPIX;
        const float* wv = wdw + vch*9;
        float a = 0.f;
        #pragma unroll
        for(int ky=0;ky<3;ky++){
            int yy = py + 2*ky - 2;
            if(yy<0||yy>=IH) continue;
            #pragma unroll
            for(int kx=0;kx<3;kx++){
                int xx = px + 2*kx - 2;
                if(xx<0||xx>=IW) continue;
                a += wv[ky*3+kx] * b2f(vbase[yy*IW+xx]);
            }
        }
        vl[hd][px_l] = a;
    }
    float acc[48];
    #pragma unroll
    for(int o=0;o<48;o++) acc[o]=0.f;
    const float* Mb = M + (size_t)b*DIM*DIM;
    for(int hc=0; hc<6; hc++){
        __syncthreads();               // hc=0: also fences phase-1 vl writes
        for(int i=tid;i<DIM*32;i+=256){
            int o = i >> 5, j = i & 31;
            Ml[o][j] = Mb[o*DIM + hc*32 + j];
        }
        __syncthreads();
        #pragma unroll 4
        for(int j=0;j<32;j++){
            float vv = vl[hc*32+j][px_l];
            #pragma unroll
            for(int o=0;o<48;o++) acc[o] += Ml[g*48+o][j]*vv;  // Ml broadcast
        }
    }
    float* op = out + ((size_t)b*DIM + g*48)*NPIX + p;
    #pragma unroll
    for(int o=0;o<48;o++) op[(size_t)o*NPIX] = acc[o];
}

// ---------------------------------------------------------------------------
extern "C" void kernel_launch(void* const* d_in, const int* in_sizes, int n_in,
                              void* d_out, int out_size, void* d_ws, size_t ws_size,
                              hipStream_t stream){
    const float* x     = (const float*)d_in[0];
    const float* wqkv  = (const float*)d_in[1];
    const float* wdw   = (const float*)d_in[2];
    const float* wproj = (const float*)d_in[3];
    const float* temp  = (const float*)d_in[4];
    float* out = (float*)d_out;

    char* ws = (char*)d_ws;
    bf16* qkv_pre = (bf16*)ws;                                   // 151 MB
    size_t off = (size_t)BATCH*QKVC*NPIX*sizeof(bf16);
    float* G   = (float*)(ws + off); off += (size_t)BATCH*NH*CH*CH*4;
    float* sqq = (float*)(ws + off); off += (size_t)BATCH*NH*CH*4;
    float* sqk = (float*)(ws + off); off += (size_t)BATCH*NH*CH*4;
    float* M   = (float*)(ws + off); off += (size_t)BATCH*DIM*DIM*4;

    // zero G + sqq + sqk (contiguous); ws is poisoned 0xAA before every launch
    hipMemsetAsync(G, 0, (size_t)(BATCH*NH*CH*CH + 2*BATCH*NH*CH)*sizeof(float),
                   stream);

    k1_qkv <<<dim3(64,12,BATCH), 256, 0, stream>>>(x, wqkv, qkv_pre);
    k2_gram<<<dim3(64,NH,BATCH), 256, 0, stream>>>(qkv_pre, wdw, G, sqq, sqk);
    k3_attn<<<BATCH, 256, 0, stream>>>(G, sqq, sqk, temp, wproj, M);
    k5_out <<<dim3(256,BATCH), 256, 0, stream>>>(qkv_pre, wdw, M, out);
}

// Round 3
// 1474.595 us; speedup vs baseline: 1.8056x; 1.8056x over previous
//
#include <hip/hip_runtime.h>

// GCSA: x(8,192,128,128) fp32 -> qkv 1x1 (MFMA) -> dw3x3 dil2 -> channel attn
//       -> proj folded into M -> out = M·v (MFMA). qkv_pre stored bf16-bits.

#define DIM 192
#define NH 8
#define CH 24
#define IH 128
#define IW 128
#define NPIX (IH*IW)
#define BATCH 8
#define QKVC (3*DIM)
#define PAD 200   // LDS row stride in shorts for [*][192] bf16 tiles (400 B)

typedef unsigned short u16;
typedef short bf16x8 __attribute__((ext_vector_type(8)));
typedef float f32x4 __attribute__((ext_vector_type(4)));

__device__ __forceinline__ float b2f(u16 u){
    unsigned v = ((unsigned)u) << 16;
    return __builtin_bit_cast(float, v);
}
__device__ __forceinline__ u16 f2b(float f){          // round-to-nearest-even
    unsigned u = __builtin_bit_cast(unsigned, f);
    u += 0x7fffu + ((u >> 16) & 1u);
    return (u16)(u >> 16);
}

// ---------------------------------------------------------------------------
// K1: qkv_pre[b][o][p] = sum_c Wqkv[o][c]*x[b][c][p], bf16 MFMA 16x16x32.
// Block: 256 thr, tile M=64(o) x N=128(p), K=192. grid (128 ptile, 9 otile, 8 b)
// ---------------------------------------------------------------------------
__global__ __launch_bounds__(256) void k1_qkv(const float* __restrict__ x,
        const float* __restrict__ wqkv, u16* __restrict__ qkv_pre){
    __shared__ __align__(16) u16 Wl[64*PAD];    // 25.6 KB
    __shared__ __align__(16) u16 Xl[128*PAD];   // 51.2 KB
    const int tid = threadIdx.x;
    const int pt = blockIdx.x, ot = blockIdx.y, b = blockIdx.z;
    const int obase = ot*64, p0 = pt*128;
    // stage W tile (fp32 -> bf16), row-major [o][c]
    for(int i = tid; i < 64*24; i += 256){
        int o = i/24, k8 = (i%24)*8;
        const float* wp = wqkv + (size_t)(obase+o)*DIM + k8;
        bf16x8 v;
        #pragma unroll
        for(int j=0;j<8;j++) v[j] = (short)f2b(wp[j]);
        *(bf16x8*)&Wl[o*PAD + k8] = v;
    }
    // stage X^T tile: Xl[px][c]; per-c coalesced fp32 loads, packed b128 writes
    {
        const int px = tid & 127, half = tid >> 7;
        const float* xb = x + (size_t)b*DIM*NPIX + p0 + px;
        for(int cg = 0; cg < 12; cg++){
            int cb = half*96 + cg*8;
            bf16x8 v;
            #pragma unroll
            for(int j=0;j<8;j++) v[j] = (short)f2b(xb[(size_t)(cb+j)*NPIX]);
            *(bf16x8*)&Xl[px*PAD + cb] = v;
        }
    }
    __syncthreads();
    const int lane = tid & 63, w = tid >> 6;
    const int r = lane & 15, quad = lane >> 4;
    const int mbase = (w & 1)*32, nbase = (w >> 1)*64;
    f32x4 acc[8];
    { f32x4 z = {0.f,0.f,0.f,0.f}; for(int i=0;i<8;i++) acc[i]=z; }
    for(int kk = 0; kk < 6; kk++){
        const int k0 = kk*32 + quad*8;
        bf16x8 a0 = *(const bf16x8*)&Wl[(mbase + r)*PAD + k0];
        bf16x8 a1 = *(const bf16x8*)&Wl[(mbase + 16 + r)*PAD + k0];
        #pragma unroll
        for(int ni=0; ni<4; ni++){
            bf16x8 bb = *(const bf16x8*)&Xl[(nbase + ni*16 + r)*PAD + k0];
            acc[ni*2+0] = __builtin_amdgcn_mfma_f32_16x16x32_bf16(a0, bb, acc[ni*2+0], 0,0,0);
            acc[ni*2+1] = __builtin_amdgcn_mfma_f32_16x16x32_bf16(a1, bb, acc[ni*2+1], 0,0,0);
        }
    }
    u16* op = qkv_pre + ((size_t)b*QKVC + obase)*NPIX + p0;
    #pragma unroll
    for(int ni=0; ni<4; ni++)
        #pragma unroll
        for(int mi=0; mi<2; mi++){
            int o_loc = mbase + mi*16 + quad*4;
            int p_loc = nbase + ni*16 + r;
            #pragma unroll
            for(int t=0;t<4;t++)
                op[(size_t)(o_loc+t)*NPIX + p_loc] = f2b(acc[ni*2+mi][t]);
        }
}

// ---------------------------------------------------------------------------
// K2: per (b,h): Gram G[c][d] over pixels + row sum-squares; dw-conv on the fly.
// grid (64 pchunk, 8 h, 8 b), block 256.
// ---------------------------------------------------------------------------
__global__ __launch_bounds__(256) void k2_gram(const u16* __restrict__ qkv_pre,
        const float* __restrict__ wdw, float* __restrict__ G,
        float* __restrict__ sqq, float* __restrict__ sqk){
    __shared__ __align__(16) float ql[CH][260];   // 25 KB
    __shared__ __align__(16) float kl[CH][260];
    const int tid = threadIdx.x;
    const int pc = blockIdx.x, h = blockIdx.y, b = blockIdx.z;
    const int p = pc*256 + tid;
    const int py = p >> 7, px = p & 127;
    for(int c=0;c<CH;c++){
        const int qch = h*CH + c;
        const int kch = DIM + qch;
        const u16* qbase = qkv_pre + ((size_t)b*QKVC + qch)*NPIX;
        const u16* kbase = qkv_pre + ((size_t)b*QKVC + kch)*NPIX;
        const float* wq = wdw + qch*9;
        const float* wk = wdw + kch*9;
        float qa=0.f, ka=0.f;
        #pragma unroll
        for(int ky=0;ky<3;ky++){
            int yy = py + 2*ky - 2;
            bool yok = (yy>=0)&&(yy<IH);
            #pragma unroll
            for(int kx=0;kx<3;kx++){
                int xx = px + 2*kx - 2;
                if(yok && xx>=0 && xx<IW){
                    int idx = yy*IW + xx;
                    qa += wq[ky*3+kx] * b2f(qbase[idx]);
                    ka += wk[ky*3+kx] * b2f(kbase[idx]);
                }
            }
        }
        ql[c][tid] = qa;
        kl[c][tid] = ka;
    }
    __syncthreads();
    if(tid < 192){
        // thread -> (c, 3 consecutive d); float4 over pixels
        int c = tid >> 3, dbase = (tid & 7)*3;
        float a0=0.f, a1=0.f, a2=0.f;
        for(int pp=0; pp<256; pp+=4){
            f32x4 qv = *(const f32x4*)&ql[c][pp];
            f32x4 k0 = *(const f32x4*)&kl[dbase  ][pp];
            f32x4 k1 = *(const f32x4*)&kl[dbase+1][pp];
            f32x4 k2 = *(const f32x4*)&kl[dbase+2][pp];
            a0 += qv[0]*k0[0] + qv[1]*k0[1] + qv[2]*k0[2] + qv[3]*k0[3];
            a1 += qv[0]*k1[0] + qv[1]*k1[1] + qv[2]*k1[2] + qv[3]*k1[3];
            a2 += qv[0]*k2[0] + qv[1]*k2[1] + qv[2]*k2[2] + qv[3]*k2[3];
        }
        float* Gp = G + ((size_t)(b*NH + h))*CH*CH + c*CH + dbase;
        atomicAdd(&Gp[0], a0);
        atomicAdd(&Gp[1], a1);
        atomicAdd(&Gp[2], a2);
    } else if(tid < 240){
        int cc = tid - 192;                       // 0..47: q rows then k rows
        const float* row = (cc < CH) ? &ql[cc][0] : &kl[cc-CH][0];
        float s = 0.f;
        for(int pp=0; pp<256; pp+=4){
            f32x4 v = *(const f32x4*)&row[pp];
            s += v[0]*v[0] + v[1]*v[1] + v[2]*v[2] + v[3]*v[3];
        }
        if(cc < CH) atomicAdd(&sqq[(b*NH+h)*CH + cc], s);
        else        atomicAdd(&sqk[(b*NH+h)*CH + (cc-CH)], s);
    }
}

// ---------------------------------------------------------------------------
// K3: softmax(G/(|q||k|)*T) folded with Wproj -> M[b][o][hd]. grid 8.
// ---------------------------------------------------------------------------
__global__ __launch_bounds__(256) void k3_attn(const float* __restrict__ G,
        const float* __restrict__ sqq, const float* __restrict__ sqk,
        const float* __restrict__ temp, const float* __restrict__ wproj,
        float* __restrict__ M){
    __shared__ float attn[NH][CH][CH];
    __shared__ float nq[DIM], nk[DIM];
    const int b = blockIdx.x, tid = threadIdx.x;
    if(tid < DIM){
        nq[tid] = fmaxf(sqrtf(sqq[b*DIM + tid]), 1e-12f);
        nk[tid] = fmaxf(sqrtf(sqk[b*DIM + tid]), 1e-12f);
    }
    __syncthreads();
    if(tid < DIM){
        int h = tid / CH, c = tid % CH;
        float t = temp[h];
        const float* g = G + ((size_t)(b*NH+h))*CH*CH + c*CH;
        float row[CH];
        float mx = -1e30f;
        #pragma unroll
        for(int d=0; d<CH; d++){
            float v = g[d] / (nq[h*CH+c]*nk[h*CH+d]) * t;
            row[d]=v; mx = fmaxf(mx,v);
        }
        float sum=0.f;
        #pragma unroll
        for(int d=0;d<CH;d++){ row[d]=expf(row[d]-mx); sum+=row[d]; }
        float inv = 1.f/sum;
        #pragma unroll
        for(int d=0;d<CH;d++) attn[h][c][d] = row[d]*inv;
    }
    __syncthreads();
    float* Mb = M + (size_t)b*DIM*DIM;
    for(int i = tid; i < DIM*DIM; i += 256){
        int o = i / DIM, hd = i % DIM;
        int h = hd / CH, d = hd % CH;
        float s = 0.f;
        #pragma unroll
        for(int c=0;c<CH;c++)
            s += wproj[o*DIM + h*CH + c] * attn[h][c][d];
        Mb[i] = s;
    }
}

// ---------------------------------------------------------------------------
// K5: out[b][o][p] = sum_hd M[b][o][hd]*v_post[b][hd][p], bf16 MFMA.
// v_post (dw conv) computed per-block straight into transposed LDS (free!).
// Block: 256 thr, tile M=64(o) x N=128(p=one image row), K=192.
// grid (128 rows, 3 otile, 8 b)
// ---------------------------------------------------------------------------
__global__ __launch_bounds__(256) void k5_out(const u16* __restrict__ qkv_pre,
        const float* __restrict__ wdw, const float* __restrict__ M,
        float* __restrict__ out){
    __shared__ __align__(16) u16 Ml[64*PAD];    // 25.6 KB
    __shared__ __align__(16) u16 vl[128*PAD];   // 51.2 KB
    const int tid = threadIdx.x;
    const int py = blockIdx.x, ot = blockIdx.y, b = blockIdx.z;
    const int obase = ot*64;
    // stage M tile (fp32 -> bf16)
    for(int i = tid; i < 64*24; i += 256){
        int o = i/24, k8 = (i%24)*8;
        const float* mp = M + ((size_t)b*DIM + obase + o)*DIM + k8;
        bf16x8 v;
        #pragma unroll
        for(int j=0;j<8;j++) v[j] = (short)f2b(mp[j]);
        *(bf16x8*)&Ml[o*PAD + k8] = v;
    }
    // dw-conv of v channels for image row py -> vl[px][hd]  (transposed, b128)
    {
        const int px = tid & 127, half = tid >> 7;
        for(int cg = 0; cg < 12; cg++){
            int cb = half*96 + cg*8;
            bf16x8 v;
            #pragma unroll
            for(int j=0;j<8;j++){
                int hd = cb + j;
                const u16* vbase = qkv_pre + ((size_t)b*QKVC + 2*DIM + hd)*NPIX;
                const float* wv = wdw + (2*DIM + hd)*9;
                float a = 0.f;
                #pragma unroll
                for(int ky=0;ky<3;ky++){
                    int yy = py + 2*ky - 2;
                    if(yy<0||yy>=IH) continue;
                    #pragma unroll
                    for(int kx=0;kx<3;kx++){
                        int xx = px + 2*kx - 2;
                        if(xx<0||xx>=IW) continue;
                        a += wv[ky*3+kx] * b2f(vbase[yy*IW + xx]);
                    }
                }
                v[j] = (short)f2b(a);
            }
            *(bf16x8*)&vl[px*PAD + cb] = v;
        }
    }
    __syncthreads();
    const int lane = tid & 63, w = tid >> 6;
    const int r = lane & 15, quad = lane >> 4;
    const int mbase = (w & 1)*32, nbase = (w >> 1)*64;
    f32x4 acc[8];
    { f32x4 z = {0.f,0.f,0.f,0.f}; for(int i=0;i<8;i++) acc[i]=z; }
    for(int kk = 0; kk < 6; kk++){
        const int k0 = kk*32 + quad*8;
        bf16x8 a0 = *(const bf16x8*)&Ml[(mbase + r)*PAD + k0];
        bf16x8 a1 = *(const bf16x8*)&Ml[(mbase + 16 + r)*PAD + k0];
        #pragma unroll
        for(int ni=0; ni<4; ni++){
            bf16x8 bb = *(const bf16x8*)&vl[(nbase + ni*16 + r)*PAD + k0];
            acc[ni*2+0] = __builtin_amdgcn_mfma_f32_16x16x32_bf16(a0, bb, acc[ni*2+0], 0,0,0);
            acc[ni*2+1] = __builtin_amdgcn_mfma_f32_16x16x32_bf16(a1, bb, acc[ni*2+1], 0,0,0);
        }
    }
    float* op = out + ((size_t)b*DIM + obase)*NPIX + py*IW;
    #pragma unroll
    for(int ni=0; ni<4; ni++)
        #pragma unroll
        for(int mi=0; mi<2; mi++){
            int o_loc = mbase + mi*16 + quad*4;
            int p_loc = nbase + ni*16 + r;
            #pragma unroll
            for(int t=0;t<4;t++)
                op[(size_t)(o_loc+t)*NPIX + p_loc] = acc[ni*2+mi][t];
        }
}

// ---------------------------------------------------------------------------
extern "C" void kernel_launch(void* const* d_in, const int* in_sizes, int n_in,
                              void* d_out, int out_size, void* d_ws, size_t ws_size,
                              hipStream_t stream){
    const float* x     = (const float*)d_in[0];
    const float* wqkv  = (const float*)d_in[1];
    const float* wdw   = (const float*)d_in[2];
    const float* wproj = (const float*)d_in[3];
    const float* temp  = (const float*)d_in[4];
    float* out = (float*)d_out;

    char* ws = (char*)d_ws;
    u16* qkv_pre = (u16*)ws;                                     // 151 MB
    size_t off = (size_t)BATCH*QKVC*NPIX*sizeof(u16);
    float* G   = (float*)(ws + off); off += (size_t)BATCH*NH*CH*CH*4;
    float* sqq = (float*)(ws + off); off += (size_t)BATCH*NH*CH*4;
    float* sqk = (float*)(ws + off); off += (size_t)BATCH*NH*CH*4;
    float* M   = (float*)(ws + off); off += (size_t)BATCH*DIM*DIM*4;

    hipMemsetAsync(G, 0, (size_t)(BATCH*NH*CH*CH + 2*BATCH*NH*CH)*sizeof(float),
                   stream);

    k1_qkv <<<dim3(128, 9, BATCH), 256, 0, stream>>>(x, wqkv, qkv_pre);
    k2_gram<<<dim3(64, NH, BATCH), 256, 0, stream>>>(qkv_pre, wdw, G, sqq, sqk);
    k3_attn<<<BATCH, 256, 0, stream>>>(G, sqq, sqk, temp, wproj, M);
    k5_out <<<dim3(128, 3, BATCH), 256, 0, stream>>>(qkv_pre, wdw, M, out);
}

// Round 4
// 526.122 us; speedup vs baseline: 5.0606x; 2.8028x over previous
//
#include <hip/hip_runtime.h>

// GCSA: x(8,192,128,128) fp32 -> qkv 1x1 (MFMA) -> dw3x3 dil2 (vectorized) ->
//       channel attn -> proj folded into M -> out = M·v_post (MFMA).
// qkv_pre bf16 in ws; v_post bf16 overwrites the q-slot after k2 consumed it.

#define DIM 192
#define NH 8
#define CH 24
#define IH 128
#define IW 128
#define NPIX (IH*IW)
#define BATCH 8
#define QKVC (3*DIM)
#define PAD 200    // u16 row stride for MFMA LDS tiles (400 B)
#define TPAD 136   // u16 row stride for k1 transpose tile (272 B, 16B-aligned)

typedef unsigned short u16;
typedef short bf16x8 __attribute__((ext_vector_type(8)));
typedef float f32x4 __attribute__((ext_vector_type(4)));

__device__ __forceinline__ float b2f(u16 u){
    unsigned v = ((unsigned)u) << 16;
    return __builtin_bit_cast(float, v);
}
__device__ __forceinline__ u16 f2b(float f){          // round-to-nearest-even
    unsigned u = __builtin_bit_cast(unsigned, f);
    u += 0x7fffu + ((u >> 16) & 1u);
    return (u16)(u >> 16);
}

// accumulate one conv row (3 taps, dilation 2) for 8 consecutive px at px0
__device__ __forceinline__ void conv_row8(const u16* __restrict__ rp, int px0,
        float w0, float w1, float w2, float* o_){
    float f[12];
    if(px0 > 0){
        unsigned u = *(const unsigned*)(rp + px0 - 2);
        f[0] = b2f((u16)u); f[1] = b2f((u16)(u >> 16));
    } else { f[0] = 0.f; f[1] = 0.f; }
    bf16x8 v = *(const bf16x8*)(rp + px0);
    #pragma unroll
    for(int j=0;j<8;j++) f[2+j] = b2f((u16)v[j]);
    if(px0 < 120){
        unsigned u = *(const unsigned*)(rp + px0 + 8);
        f[10] = b2f((u16)u); f[11] = b2f((u16)(u >> 16));
    } else { f[10] = 0.f; f[11] = 0.f; }
    #pragma unroll
    for(int i=0;i<8;i++) o_[i] += w0*f[i] + w1*f[i+2] + w2*f[i+4];
}

// ---------------------------------------------------------------------------
// K1: qkv_pre[b][o][p] = sum_c Wqkv[o][c]*x[b][c][p].  MFMA 16x16x32 bf16.
// Block: 256 thr, N=128 px staged ONCE, loop 9 o-tiles of 64. grid (128,8).
// ---------------------------------------------------------------------------
__global__ __launch_bounds__(256) void k1_qkv(const float* __restrict__ x,
        const float* __restrict__ wqkv, u16* __restrict__ qkv_pre){
    __shared__ __align__(16) u16 Xl[128*PAD];   // 51.2 KB
    __shared__ __align__(16) u16 Wl[64*PAD];    // 25.6 KB (reused as Tl[64*TPAD])
    const int tid = threadIdx.x;
    const int pt = blockIdx.x, b = blockIdx.y;
    const int p0 = pt*128;
    // stage X^T: Xl[px][c] (coalesced fp32 column loads, packed b128 writes)
    {
        const int px = tid & 127, half = tid >> 7;
        const float* xb = x + (size_t)b*DIM*NPIX + p0 + px;
        for(int cg = 0; cg < 12; cg++){
            int cb = half*96 + cg*8;
            bf16x8 v;
            #pragma unroll
            for(int j=0;j<8;j++) v[j] = (short)f2b(xb[(size_t)(cb+j)*NPIX]);
            *(bf16x8*)&Xl[px*PAD + cb] = v;
        }
    }
    const int lane = tid & 63, w = tid >> 6;
    const int r = lane & 15, quad = lane >> 4;
    const int mbase = (w & 1)*32, nbase = (w >> 1)*64;
    u16* Tl = Wl;
    for(int ot = 0; ot < 9; ot++){
        const int obase = ot*64;
        for(int i = tid; i < 64*24; i += 256){
            int o = i/24, k8 = (i%24)*8;
            const float* wp = wqkv + (size_t)(obase+o)*DIM + k8;
            bf16x8 v;
            #pragma unroll
            for(int j=0;j<8;j++) v[j] = (short)f2b(wp[j]);
            *(bf16x8*)&Wl[o*PAD + k8] = v;
        }
        __syncthreads();   // Wl ready (and Xl on ot=0)
        f32x4 acc[8];
        { f32x4 z = {0.f,0.f,0.f,0.f}; for(int i=0;i<8;i++) acc[i]=z; }
        #pragma unroll
        for(int kk = 0; kk < 6; kk++){
            const int k0 = kk*32 + quad*8;
            bf16x8 a0 = *(const bf16x8*)&Wl[(mbase + r)*PAD + k0];
            bf16x8 a1 = *(const bf16x8*)&Wl[(mbase + 16 + r)*PAD + k0];
            #pragma unroll
            for(int ni=0; ni<4; ni++){
                bf16x8 bb = *(const bf16x8*)&Xl[(nbase + ni*16 + r)*PAD + k0];
                acc[ni*2+0] = __builtin_amdgcn_mfma_f32_16x16x32_bf16(a0, bb, acc[ni*2+0], 0,0,0);
                acc[ni*2+1] = __builtin_amdgcn_mfma_f32_16x16x32_bf16(a1, bb, acc[ni*2+1], 0,0,0);
            }
        }
        __syncthreads();   // done reading Wl -> can overwrite with Tl
        #pragma unroll
        for(int ni=0; ni<4; ni++)
            #pragma unroll
            for(int mi=0; mi<2; mi++){
                int o_loc = mbase + mi*16 + quad*4;
                int p_loc = nbase + ni*16 + r;
                #pragma unroll
                for(int t=0;t<4;t++)
                    Tl[(o_loc+t)*TPAD + p_loc] = f2b(acc[ni*2+mi][t]);
            }
        __syncthreads();   // Tl ready
        u16* op = qkv_pre + ((size_t)b*QKVC + obase)*NPIX + p0;
        for(int it = 0; it < 4; it++){
            int idx = tid + it*256;          // 1024 b128 chunks
            int o = idx >> 4, oct = idx & 15;
            bf16x8 v = *(const bf16x8*)&Tl[o*TPAD + oct*8];
            *(bf16x8*)&op[(size_t)o*NPIX + oct*8] = v;
        }
        __syncthreads();   // done reading Tl -> next ot may overwrite Wl
    }
}

// ---------------------------------------------------------------------------
// K2: per (b,h): Gram G[c][d] + row sum-squares; dw-conv vectorized inline.
// Block = 256 px (2 rows). Tasks: 48 ch(q+k) x 32 octets -> 6 tasks/thread.
// grid (64 pchunk, 8 h, 8 b).
// ---------------------------------------------------------------------------
__global__ __launch_bounds__(256) void k2_gram(const u16* __restrict__ qkv_pre,
        const float* __restrict__ wdw, float* __restrict__ G,
        float* __restrict__ sqq, float* __restrict__ sqk){
    __shared__ __align__(16) float ql[CH][260];   // 25 KB
    __shared__ __align__(16) float kl[CH][260];
    const int tid = threadIdx.x;
    const int pc = blockIdx.x, h = blockIdx.y, b = blockIdx.z;
    const int py0 = (pc*256) >> 7;
    for(int it = 0; it < 6; it++){
        int t = tid + it*256;                 // 0..1535
        int c48 = t >> 5, oct = t & 31;
        int isK = (c48 >= CH);
        int c = isK ? (c48 - CH) : c48;
        int ch = (isK ? DIM : 0) + h*CH + c;
        const u16* base = qkv_pre + ((size_t)b*QKVC + ch)*NPIX;
        const float* wv = wdw + ch*9;
        int py = py0 + (oct >> 4);
        int px0 = (oct & 15)*8;
        float o_[8];
        #pragma unroll
        for(int i=0;i<8;i++) o_[i]=0.f;
        #pragma unroll
        for(int ky=0;ky<3;ky++){
            int ry = py + 2*ky - 2;
            if(ry < 0 || ry >= IH) continue;
            conv_row8(base + ry*IW, px0, wv[ky*3], wv[ky*3+1], wv[ky*3+2], o_);
        }
        float* dst = (isK ? &kl[c][0] : &ql[c][0]) + oct*8;
        f32x4 v0 = {o_[0],o_[1],o_[2],o_[3]};
        f32x4 v1 = {o_[4],o_[5],o_[6],o_[7]};
        *(f32x4*)&dst[0] = v0;
        *(f32x4*)&dst[4] = v1;
    }
    __syncthreads();
    if(tid < 192){
        int c = tid >> 3, dbase = (tid & 7)*3;
        float a0=0.f, a1=0.f, a2=0.f;
        for(int pp=0; pp<256; pp+=4){
            f32x4 qv = *(const f32x4*)&ql[c][pp];
            f32x4 k0 = *(const f32x4*)&kl[dbase  ][pp];
            f32x4 k1 = *(const f32x4*)&kl[dbase+1][pp];
            f32x4 k2 = *(const f32x4*)&kl[dbase+2][pp];
            a0 += qv[0]*k0[0] + qv[1]*k0[1] + qv[2]*k0[2] + qv[3]*k0[3];
            a1 += qv[0]*k1[0] + qv[1]*k1[1] + qv[2]*k1[2] + qv[3]*k1[3];
            a2 += qv[0]*k2[0] + qv[1]*k2[1] + qv[2]*k2[2] + qv[3]*k2[3];
        }
        float* Gp = G + ((size_t)(b*NH + h))*CH*CH + c*CH + dbase;
        atomicAdd(&Gp[0], a0);
        atomicAdd(&Gp[1], a1);
        atomicAdd(&Gp[2], a2);
    } else if(tid < 240){
        int cc = tid - 192;
        const float* row = (cc < CH) ? &ql[cc][0] : &kl[cc-CH][0];
        float s = 0.f;
        for(int pp=0; pp<256; pp+=4){
            f32x4 v = *(const f32x4*)&row[pp];
            s += v[0]*v[0] + v[1]*v[1] + v[2]*v[2] + v[3]*v[3];
        }
        if(cc < CH) atomicAdd(&sqq[(b*NH+h)*CH + cc], s);
        else        atomicAdd(&sqk[(b*NH+h)*CH + (cc-CH)], s);
    }
}

// ---------------------------------------------------------------------------
// K4: v_post = dw-conv(v_pre), vectorized; written over the q-slot (ch 0..191)
// of qkv_pre (k2 already consumed q). grid (8 bands, 96 chpairs, 8 b).
// thread = (16 py rows x 16 px octets), 2 channels each.
// ---------------------------------------------------------------------------
__global__ __launch_bounds__(256) void k4_vconv(u16* __restrict__ qkv_pre,
        const float* __restrict__ wdw){
    const int tid = threadIdx.x;
    const int oct = tid & 15, pyl = tid >> 4;
    const int band = blockIdx.x, cp = blockIdx.y, b = blockIdx.z;
    const int py = band*16 + pyl, px0 = oct*8;
    #pragma unroll
    for(int j=0;j<2;j++){
        int ch = cp*2 + j;
        const u16* base = qkv_pre + ((size_t)b*QKVC + 2*DIM + ch)*NPIX;
        const float* wv = wdw + (2*DIM + ch)*9;
        float o_[8];
        #pragma unroll
        for(int i=0;i<8;i++) o_[i]=0.f;
        #pragma unroll
        for(int ky=0;ky<3;ky++){
            int ry = py + 2*ky - 2;
            if(ry < 0 || ry >= IH) continue;
            conv_row8(base + ry*IW, px0, wv[ky*3], wv[ky*3+1], wv[ky*3+2], o_);
        }
        bf16x8 v;
        #pragma unroll
        for(int i=0;i<8;i++) v[i] = (short)f2b(o_[i]);
        *(bf16x8*)&qkv_pre[((size_t)b*QKVC + ch)*NPIX + py*IW + px0] = v;
    }
}

// ---------------------------------------------------------------------------
// K3: softmax(G/(|q||k|)*T) folded with Wproj -> M[b][o][hd]. grid 8.
// ---------------------------------------------------------------------------
__global__ __launch_bounds__(256) void k3_attn(const float* __restrict__ G,
        const float* __restrict__ sqq, const float* __restrict__ sqk,
        const float* __restrict__ temp, const float* __restrict__ wproj,
        float* __restrict__ M){
    __shared__ float attn[NH][CH][CH];
    __shared__ float nq[DIM], nk[DIM];
    const int b = blockIdx.x, tid = threadIdx.x;
    if(tid < DIM){
        nq[tid] = fmaxf(sqrtf(sqq[b*DIM + tid]), 1e-12f);
        nk[tid] = fmaxf(sqrtf(sqk[b*DIM + tid]), 1e-12f);
    }
    __syncthreads();
    if(tid < DIM){
        int h = tid / CH, c = tid % CH;
        float t = temp[h];
        const float* g = G + ((size_t)(b*NH+h))*CH*CH + c*CH;
        float row[CH];
        float mx = -1e30f;
        #pragma unroll
        for(int d=0; d<CH; d++){
            float v = g[d] / (nq[h*CH+c]*nk[h*CH+d]) * t;
            row[d]=v; mx = fmaxf(mx,v);
        }
        float sum=0.f;
        #pragma unroll
        for(int d=0;d<CH;d++){ row[d]=expf(row[d]-mx); sum+=row[d]; }
        float inv = 1.f/sum;
        #pragma unroll
        for(int d=0;d<CH;d++) attn[h][c][d] = row[d]*inv;
    }
    __syncthreads();
    float* Mb = M + (size_t)b*DIM*DIM;
    for(int i = tid; i < DIM*DIM; i += 256){
        int o = i / DIM, hd = i % DIM;
        int h = hd / CH, d = hd % CH;
        float s = 0.f;
        #pragma unroll
        for(int c=0;c<CH;c++)
            s += wproj[o*DIM + h*CH + c] * attn[h][c][d];
        Mb[i] = s;
    }
}

// ---------------------------------------------------------------------------
// K5: out[b][o][p] = sum_hd M[b][o][hd]*v_post[b][hd][p].  Pure MFMA GEMM.
// vl staged once (coalesced u16 column loads), loop 3 o-tiles. grid (128,8).
// ---------------------------------------------------------------------------
__global__ __launch_bounds__(256) void k5_out(const u16* __restrict__ qkv_pre,
        const float* __restrict__ M, float* __restrict__ out){
    __shared__ __align__(16) u16 vl[128*PAD];   // 51.2 KB
    __shared__ __align__(16) u16 Ml[64*PAD];    // 25.6 KB
    const int tid = threadIdx.x;
    const int py = blockIdx.x, b = blockIdx.y;
    const int p0 = py*IW;
    // stage v^T: vl[px][ch] from v_post (q-slot, ch 0..191)
    {
        const int px = tid & 127, half = tid >> 7;
        const u16* vb = qkv_pre + (size_t)b*QKVC*NPIX + p0 + px;
        for(int cg = 0; cg < 12; cg++){
            int cb = half*96 + cg*8;
            bf16x8 v;
            #pragma unroll
            for(int j=0;j<8;j++) v[j] = (short)vb[(size_t)(cb+j)*NPIX];
            *(bf16x8*)&vl[px*PAD + cb] = v;
        }
    }
    const int lane = tid & 63, w = tid >> 6;
    const int r = lane & 15, quad = lane >> 4;
    const int mbase = (w & 1)*32, nbase = (w >> 1)*64;
    for(int ot = 0; ot < 3; ot++){
        const int obase = ot*64;
        for(int i = tid; i < 64*24; i += 256){
            int o = i/24, k8 = (i%24)*8;
            const float* mp = M + ((size_t)b*DIM + obase + o)*DIM + k8;
            bf16x8 v;
            #pragma unroll
            for(int j=0;j<8;j++) v[j] = (short)f2b(mp[j]);
            *(bf16x8*)&Ml[o*PAD + k8] = v;
        }
        __syncthreads();   // Ml ready (and vl on ot=0)
        f32x4 acc[8];
        { f32x4 z = {0.f,0.f,0.f,0.f}; for(int i=0;i<8;i++) acc[i]=z; }
        #pragma unroll
        for(int kk = 0; kk < 6; kk++){
            const int k0 = kk*32 + quad*8;
            bf16x8 a0 = *(const bf16x8*)&Ml[(mbase + r)*PAD + k0];
            bf16x8 a1 = *(const bf16x8*)&Ml[(mbase + 16 + r)*PAD + k0];
            #pragma unroll
            for(int ni=0; ni<4; ni++){
                bf16x8 bb = *(const bf16x8*)&vl[(nbase + ni*16 + r)*PAD + k0];
                acc[ni*2+0] = __builtin_amdgcn_mfma_f32_16x16x32_bf16(a0, bb, acc[ni*2+0], 0,0,0);
                acc[ni*2+1] = __builtin_amdgcn_mfma_f32_16x16x32_bf16(a1, bb, acc[ni*2+1], 0,0,0);
            }
        }
        float* op = out + ((size_t)b*DIM + obase)*NPIX + p0;
        #pragma unroll
        for(int ni=0; ni<4; ni++)
            #pragma unroll
            for(int mi=0; mi<2; mi++){
                int o_loc = mbase + mi*16 + quad*4;
                int p_loc = nbase + ni*16 + r;
                #pragma unroll
                for(int t=0;t<4;t++)
                    op[(size_t)(o_loc+t)*NPIX + p_loc] = acc[ni*2+mi][t];
            }
        __syncthreads();   // done with Ml -> next ot restages
    }
}

// ---------------------------------------------------------------------------
extern "C" void kernel_launch(void* const* d_in, const int* in_sizes, int n_in,
                              void* d_out, int out_size, void* d_ws, size_t ws_size,
                              hipStream_t stream){
    const float* x     = (const float*)d_in[0];
    const float* wqkv  = (const float*)d_in[1];
    const float* wdw   = (const float*)d_in[2];
    const float* wproj = (const float*)d_in[3];
    const float* temp  = (const float*)d_in[4];
    float* out = (float*)d_out;

    char* ws = (char*)d_ws;
    u16* qkv_pre = (u16*)ws;                                     // 151 MB
    size_t off = (size_t)BATCH*QKVC*NPIX*sizeof(u16);
    float* G   = (float*)(ws + off); off += (size_t)BATCH*NH*CH*CH*4;
    float* sqq = (float*)(ws + off); off += (size_t)BATCH*NH*CH*4;
    float* sqk = (float*)(ws + off); off += (size_t)BATCH*NH*CH*4;
    float* M   = (float*)(ws + off); off += (size_t)BATCH*DIM*DIM*4;

    hipMemsetAsync(G, 0, (size_t)(BATCH*NH*CH*CH + 2*BATCH*NH*CH)*sizeof(float),
                   stream);

    k1_qkv <<<dim3(128, BATCH), 256, 0, stream>>>(x, wqkv, qkv_pre);
    k2_gram<<<dim3(64, NH, BATCH), 256, 0, stream>>>(qkv_pre, wdw, G, sqq, sqk);
    // k4 overwrites q-slot with v_post -- must run AFTER k2 consumed q.
    k4_vconv<<<dim3(8, 96, BATCH), 256, 0, stream>>>(qkv_pre, wdw);
    k3_attn<<<BATCH, 256, 0, stream>>>(G, sqq, sqk, temp, wproj, M);
    k5_out <<<dim3(128, BATCH), 256, 0, stream>>>(qkv_pre, M, out);
}